// Round 2
// baseline (274.411 us; speedup 1.0000x reference)
//
#include <hip/hip_runtime.h>
#include <stdint.h>

#define Bb 16
#define Nn 1024
#define Hh 8
#define Dd 64

typedef unsigned short u16;
typedef float f32x4 __attribute__((ext_vector_type(4)));
typedef short short8 __attribute__((ext_vector_type(8)));

__device__ __forceinline__ uint32_t f2bf(float f){
  union{float f;uint32_t i;} v; v.f=f;
  return (v.i + 0x7fffu + ((v.i>>16)&1u))>>16;
}

__device__ __forceinline__ f32x4 mfma16(short8 a, short8 b, f32x4 c){
  return __builtin_amdgcn_mfma_f32_16x16x32_bf16(a,b,c,0,0,0);
}

// log2(10000)/32
#define ROPE_K 0.41524101186092030f

__global__ void rope_table_kernel(float2* __restrict__ tab){
  int id = blockIdx.x*256 + threadIdx.x;      // 0..32767 -> (n, i)
  int n = id >> 5, i = id & 31;
  float inv = exp2f(-(float)i * ROPE_K);
  float a = (float)n * inv;
  float s, c; sincosf(a, &s, &c);
  tab[id] = make_float2(c, s);
}

// Load 16 f32 from src (row base + d0), apply RoPE in f32, store 16 bf16 to LDS.
template<bool USE_TABLE>
__device__ __forceinline__ void stage_rope_row(const float* __restrict__ src,
                                               u16 (*dst)[72],
                                               const float2* __restrict__ tab,
                                               int n_global, int sr, int d0)
{
  const float4* g = (const float4*)src;
  float4 a0 = g[0], a1 = g[1], a2 = g[2], a3 = g[3];
  float xx[16] = {a0.x,a0.y,a0.z,a0.w, a1.x,a1.y,a1.z,a1.w,
                  a2.x,a2.y,a2.z,a2.w, a3.x,a3.y,a3.z,a3.w};
  float2 cs[8];
  if (USE_TABLE){
    const float2* t = tab + (n_global<<5) + (d0>>1);
    #pragma unroll
    for (int j=0;j<8;++j) cs[j] = t[j];
  } else {
    #pragma unroll
    for (int j=0;j<8;++j){
      int i = (d0>>1)+j;
      float inv = exp2f(-(float)i * ROPE_K);
      float a = (float)n_global * inv;
      sincosf(a, &cs[j].y, &cs[j].x);
    }
  }
  uint32_t w[8];
  #pragma unroll
  for (int j=0;j<8;++j){
    float x0 = xx[2*j], x1 = xx[2*j+1];
    float q0 = x0*cs[j].x - x1*cs[j].y;
    float q1 = x1*cs[j].x + x0*cs[j].y;
    w[j] = f2bf(q0) | (f2bf(q1)<<16);
  }
  *(uint4*)&dst[sr][d0]   = make_uint4(w[0],w[1],w[2],w[3]);
  *(uint4*)&dst[sr][d0+8] = make_uint4(w[4],w[5],w[6],w[7]);
}

template<bool USE_TABLE>
__global__ __launch_bounds__(256,2) void attn_kernel(
    const float* __restrict__ xq, const float* __restrict__ xk,
    const float* __restrict__ xv, const int* __restrict__ vis,
    const float2* __restrict__ tab, float* __restrict__ out)
{
  __shared__ u16 Qs[64][72];        // roped Q tile (bf16 bits)
  __shared__ u16 Ks[64][72];        // roped K tile
  __shared__ u16 Vt[64][72];        // V transposed: Vt[d][k_local]
  __shared__ u16 Ps[4][16][72];     // per-wave P scratch (C->A layout xform)
  __shared__ float viss[64];        // key visibility for current tile

  const int tid  = threadIdx.x;
  const int wave = tid >> 6;
  const int lane = tid & 63;
  const int l15  = lane & 15;
  const int quad = lane >> 4;

  const int bid = blockIdx.x;
  const int qt = bid & 15;          // q tile (64 rows)
  const int h  = (bid >> 4) & 7;
  const int b  = bid >> 7;

  const int sr = tid >> 2;          // staging row 0..63
  const int d0 = (tid & 3) << 4;    // staging col 0/16/32/48

  // ---- stage roped Q ----
  {
    int ng = (qt<<6) + sr;
    const float* src = xq + ((((size_t)b*Nn + ng)*Hh + h)<<6) + d0;
    stage_rope_row<USE_TABLE>(src, Qs, tab, ng, sr, d0);
  }
  __syncthreads();

  // per-wave Q A-fragments: A[m=lane&15][k=quad*8+j (+32)]
  short8 qa0 = *(const short8*)&Qs[(wave<<4)+l15][quad<<3];
  short8 qa1 = *(const short8*)&Qs[(wave<<4)+l15][(quad<<3)+32];

  f32x4 acc[4];
  #pragma unroll
  for (int s=0;s<4;++s) acc[s] = (f32x4){0.f,0.f,0.f,0.f};
  float m_r[4], l_r[4];
  #pragma unroll
  for (int rr=0;rr<4;++rr){ m_r[rr] = -1e30f; l_r[rr] = 0.f; }

  for (int kt=0; kt<16; ++kt){
    __syncthreads();   // previous tile fully consumed
    // ---- stage roped K ----
    {
      int ng = (kt<<6) + sr;
      const float* src = xk + ((((size_t)b*Nn + ng)*Hh + h)<<6) + d0;
      stage_rope_row<USE_TABLE>(src, Ks, tab, ng, sr, d0);
    }
    // ---- stage V transposed (f32 -> bf16) ----
    {
      int ng = (kt<<6) + sr;
      const float4* g = (const float4*)(xv + ((((size_t)b*Nn + ng)*Hh + h)<<6) + d0);
      float4 a0 = g[0], a1 = g[1], a2 = g[2], a3 = g[3];
      float vv16[16] = {a0.x,a0.y,a0.z,a0.w, a1.x,a1.y,a1.z,a1.w,
                        a2.x,a2.y,a2.z,a2.w, a3.x,a3.y,a3.z,a3.w};
      #pragma unroll
      for (int j=0;j<16;++j) Vt[d0+j][sr] = (u16)f2bf(vv16[j]);
    }
    if (tid < 64) viss[tid] = (vis[b*Nn + (kt<<6) + tid] != 0) ? 1.f : 0.f;
    __syncthreads();

    // ---- S = Q K^T (per-wave 16x64) ----
    f32x4 s4[4];
    #pragma unroll
    for (int n=0;n<4;++n){
      short8 kb0 = *(const short8*)&Ks[(n<<4)+l15][quad<<3];
      short8 kb1 = *(const short8*)&Ks[(n<<4)+l15][(quad<<3)+32];
      f32x4 t = (f32x4){0.f,0.f,0.f,0.f};
      t = mfma16(qa0, kb0, t);
      t = mfma16(qa1, kb1, t);
      s4[n] = t;
    }
    float vv[4];
    #pragma unroll
    for (int n=0;n<4;++n) vv[n] = viss[(n<<4)+l15];

    // ---- online softmax (C layout: row=quad*4+rr, col=n*16+l15) ----
    float p[4][4];
    #pragma unroll
    for (int rr=0; rr<4; ++rr){
      float sc[4];
      #pragma unroll
      for (int n=0;n<4;++n) sc[n] = (vv[n] > 0.f) ? s4[n][rr]*0.125f : -1e30f;
      float tm = fmaxf(fmaxf(sc[0],sc[1]), fmaxf(sc[2],sc[3]));
      tm = fmaxf(tm, __shfl_xor(tm,1));
      tm = fmaxf(tm, __shfl_xor(tm,2));
      tm = fmaxf(tm, __shfl_xor(tm,4));
      tm = fmaxf(tm, __shfl_xor(tm,8));
      float mnew  = fmaxf(m_r[rr], tm);
      float alpha = __expf(m_r[rr] - mnew);
      m_r[rr] = mnew;
      float psum = 0.f;
      #pragma unroll
      for (int n=0;n<4;++n){
        float pv = (vv[n] > 0.f) ? __expf(sc[n] - mnew) : 0.f;
        p[n][rr] = pv; psum += pv;
      }
      l_r[rr] = l_r[rr]*alpha + psum;
      #pragma unroll
      for (int s=0;s<4;++s) acc[s][rr] *= alpha;
    }

    // ---- P: C-layout regs -> LDS -> A-layout frags (wave-private scratch) ----
    #pragma unroll
    for (int n=0;n<4;++n)
      #pragma unroll
      for (int rr=0;rr<4;++rr)
        Ps[wave][(quad<<2)+rr][(n<<4)+l15] = (u16)f2bf(p[n][rr]);
    asm volatile("s_waitcnt lgkmcnt(0)" ::: "memory");
    short8 pa0 = *(const short8*)&Ps[wave][l15][quad<<3];
    short8 pa1 = *(const short8*)&Ps[wave][l15][(quad<<3)+32];

    // ---- O += P V ----
    #pragma unroll
    for (int s=0;s<4;++s){
      short8 vb0 = *(const short8*)&Vt[(s<<4)+l15][quad<<3];
      short8 vb1 = *(const short8*)&Vt[(s<<4)+l15][(quad<<3)+32];
      acc[s] = mfma16(pa0, vb0, acc[s]);
      acc[s] = mfma16(pa1, vb1, acc[s]);
    }
  }

  // ---- epilogue: normalize, apply query mask, store f32 ----
  #pragma unroll
  for (int rr=0;rr<4;++rr){
    float t = l_r[rr];
    t += __shfl_xor(t,1); t += __shfl_xor(t,2);
    t += __shfl_xor(t,4); t += __shfl_xor(t,8);
    int row = (qt<<6) + (wave<<4) + (quad<<2) + rr;
    int qv  = vis[b*Nn + row];
    float invl = (qv != 0 && t > 0.f) ? 1.f/t : 0.f;   // masked query or empty row -> 0
    size_t obase = (((size_t)b*Nn + row)*Hh + h) << 6;
    #pragma unroll
    for (int s=0;s<4;++s)
      out[obase + (s<<4) + l15] = acc[s][rr]*invl;
  }
}

extern "C" void kernel_launch(void* const* d_in, const int* in_sizes, int n_in,
                              void* d_out, int out_size, void* d_ws, size_t ws_size,
                              hipStream_t stream)
{
  const float* xq = (const float*)d_in[0];
  const float* xk = (const float*)d_in[1];
  const float* xv = (const float*)d_in[2];
  const int* vis  = (const int*)d_in[3];
  float* out = (float*)d_out;

  const size_t tab_bytes = (size_t)Nn*32*sizeof(float2);   // 256 KB
  const int grid = Bb*Hh*(Nn/64);                           // 2048 blocks

  if (d_ws != nullptr && ws_size >= tab_bytes){
    float2* tab = (float2*)d_ws;
    rope_table_kernel<<<dim3((Nn*32)/256), dim3(256), 0, stream>>>(tab);
    attn_kernel<true><<<dim3(grid), dim3(256), 0, stream>>>(xq,xk,xv,vis,tab,out);
  } else {
    attn_kernel<false><<<dim3(grid), dim3(256), 0, stream>>>(xq,xk,xv,vis,nullptr,out);
  }
}

// Round 3
// 195.814 us; speedup vs baseline: 1.4014x; 1.4014x over previous
//
#include <hip/hip_runtime.h>
#include <stdint.h>

#define Bb 16
#define Nn 1024
#define Hh 8
#define Dd 64

typedef unsigned short u16;
typedef float f32x4 __attribute__((ext_vector_type(4)));
typedef short short8 __attribute__((ext_vector_type(8)));

union U4S8 { uint4 u; short8 s; };

__device__ __forceinline__ uint32_t f2bf(float f){
  union{float f;uint32_t i;} v; v.f=f;
  return (v.i + 0x7fffu + ((v.i>>16)&1u))>>16;
}

__device__ __forceinline__ f32x4 mfma16(short8 a, short8 b, f32x4 c){
  return __builtin_amdgcn_mfma_f32_16x16x32_bf16(a,b,c,0,0,0);
}

// log2(10000)/32
#define ROPE_K 0.41524101186092030f

// ============================================================
// Prepass: rope K -> bf16 [b][h][n][d]; transpose V -> bf16 [b][h][d][n]
// grid: 2048 = (b,h,nt), 256 threads
// ============================================================
__global__ __launch_bounds__(256) void prepass_kernel(
    const float* __restrict__ xk, const float* __restrict__ xv,
    u16* __restrict__ Kr, u16* __restrict__ Vt)
{
  const int tid = threadIdx.x;
  const int bid = blockIdx.x;
  const int nt = bid & 15, h = (bid>>4)&7, b = bid>>7;
  const size_t bh = (size_t)b*Hh + h;

  // ---- K rope: thread -> row r, 16 cols at c ----
  {
    int r = tid>>2, c = (tid&3)<<4;
    int n = (nt<<6) + r;
    const float4* g = (const float4*)(xk + ((((size_t)b*Nn + n)*Hh + h)<<6) + c);
    float4 a0=g[0],a1=g[1],a2=g[2],a3=g[3];
    float xx[16] = {a0.x,a0.y,a0.z,a0.w, a1.x,a1.y,a1.z,a1.w,
                    a2.x,a2.y,a2.z,a2.w, a3.x,a3.y,a3.z,a3.w};
    uint32_t w[8];
    #pragma unroll
    for (int j=0;j<8;++j){
      int i = (c>>1)+j;
      float inv = exp2f(-(float)i * ROPE_K);
      float ang = (float)n * inv;
      float sn, cs; sincosf(ang, &sn, &cs);
      float x0 = xx[2*j], x1 = xx[2*j+1];
      float q0 = x0*cs - x1*sn;
      float q1 = x1*cs + x0*sn;
      w[j] = f2bf(q0) | (f2bf(q1)<<16);
    }
    u16* dst = Kr + ((bh<<10) + n - ((size_t)0))*0; // (avoid miscompute; real below)
    dst = Kr + (((bh<<10) + (size_t)n)<<6) + c;
    *(uint4*)dst     = make_uint4(w[0],w[1],w[2],w[3]);
    *(uint4*)(dst+8) = make_uint4(w[4],w[5],w[6],w[7]);
  }

  // ---- V transpose: thread -> key k, d-strip of 16 ----
  {
    int k = tid&63, dstrip = (tid>>6)<<4;
    int n = (nt<<6) + k;
    const float4* g = (const float4*)(xv + ((((size_t)b*Nn + n)*Hh + h)<<6) + dstrip);
    float4 a0=g[0],a1=g[1],a2=g[2],a3=g[3];
    float vv[16] = {a0.x,a0.y,a0.z,a0.w, a1.x,a1.y,a1.z,a1.w,
                    a2.x,a2.y,a2.z,a2.w, a3.x,a3.y,a3.z,a3.w};
    #pragma unroll
    for (int j=0;j<16;++j)
      Vt[ ((bh<<6) + (size_t)(dstrip+j))*Nn + n ] = (u16)f2bf(vv[j]);
  }
}

// ============================================================
// Main attention: 1024 blocks = (b,h,qt of 128 rows), 256 threads,
// wave owns 32 q-rows (2 m-blocks). Deferred softmax (no online max).
// ============================================================
__global__ __launch_bounds__(256,3) void attn2_kernel(
    const float* __restrict__ xq, const u16* __restrict__ Kr,
    const u16* __restrict__ Vt, const int* __restrict__ vis,
    float* __restrict__ out)
{
  __shared__ u16 Ks[64][72];        // roped K tile [key][d]
  __shared__ u16 Vs[64][72];        // V^T tile [d][key]
  __shared__ u16 Ps[4][32][64];     // per-wave P scratch, XOR-swizzled cols

  const int tid  = threadIdx.x;
  const int wave = tid >> 6;
  const int lane = tid & 63;
  const int l15  = lane & 15;
  const int quad = lane >> 4;

  const int bid = blockIdx.x;
  const int qt = bid & 7;
  const int h  = (bid >> 3) & 7;
  const int b  = bid >> 6;
  const size_t bh = (size_t)b*Hh + h;

  // ---- roped Q A-frags in registers (sm_scale 0.125 folded in) ----
  short8 qa[2][2];
  #pragma unroll
  for (int mb=0; mb<2; ++mb){
    int n = (qt<<7) + (wave<<5) + (mb<<4) + l15;    // q row
    const float* src = xq + ((((size_t)b*Nn + n)*Hh + h)<<6);
    #pragma unroll
    for (int half=0; half<2; ++half){
      int d0 = (quad<<3) + (half<<5);
      const float4* g = (const float4*)(src + d0);
      float4 u0 = g[0], u1 = g[1];
      float xx[8] = {u0.x,u0.y,u0.z,u0.w, u1.x,u1.y,u1.z,u1.w};
      uint32_t w[4];
      #pragma unroll
      for (int j=0;j<4;++j){
        int i = (d0>>1) + j;
        float inv = exp2f(-(float)i * ROPE_K);
        float ang = (float)n * inv;
        float sn, cs; sincosf(ang, &sn, &cs);
        float x0 = xx[2*j], x1 = xx[2*j+1];
        float q0 = (x0*cs - x1*sn)*0.125f;
        float q1 = (x1*cs + x0*sn)*0.125f;
        w[j] = f2bf(q0) | (f2bf(q1)<<16);
      }
      U4S8 t; t.u = make_uint4(w[0],w[1],w[2],w[3]);
      qa[mb][half] = t.s;
    }
  }

  f32x4 acc[2][4];
  float l_r[2][4];
  #pragma unroll
  for (int mb=0;mb<2;++mb){
    #pragma unroll
    for (int s=0;s<4;++s) acc[mb][s] = (f32x4){0.f,0.f,0.f,0.f};
    #pragma unroll
    for (int rr=0;rr<4;++rr) l_r[mb][rr] = 0.f;
  }

  const u16* Krb = Kr + (bh<<16);
  const u16* Vtb = Vt + (bh<<16);
  const int* visb = vis + b*Nn;

  const int r = tid>>2, c16 = (tid&3)<<4;
  const int sw = l15>>2;            // Ps read-side swizzle key

  for (int kt=0; kt<16; ++kt){
    __syncthreads();
    // ---- stage K,V tiles (pure bf16 copies) ----
    {
      const u16* ksrc = Krb + ((size_t)((kt<<6)+r)<<6) + c16;
      uint4 k0 = *(const uint4*)ksrc, k1 = *(const uint4*)(ksrc+8);
      const u16* vsrc = Vtb + ((size_t)r<<10) + (kt<<6) + c16;
      uint4 v0 = *(const uint4*)vsrc, v1 = *(const uint4*)(vsrc+8);
      *(uint4*)&Ks[r][c16]   = k0; *(uint4*)&Ks[r][c16+8] = k1;
      *(uint4*)&Vs[r][c16]   = v0; *(uint4*)&Vs[r][c16+8] = v1;
    }
    __syncthreads();

    // ---- S = Q K^T : 2 m-blocks x 4 n-blocks ----
    f32x4 s4[2][4];
    #pragma unroll
    for (int n=0;n<4;++n){
      short8 kb0 = *(const short8*)&Ks[(n<<4)+l15][quad<<3];
      short8 kb1 = *(const short8*)&Ks[(n<<4)+l15][(quad<<3)+32];
      #pragma unroll
      for (int mb=0;mb<2;++mb){
        f32x4 t = (f32x4){0.f,0.f,0.f,0.f};
        t = mfma16(qa[mb][0], kb0, t);
        t = mfma16(qa[mb][1], kb1, t);
        s4[mb][n] = t;
      }
    }

    float vf[4];
    #pragma unroll
    for (int n=0;n<4;++n)
      vf[n] = (visb[(kt<<6)+(n<<4)+l15] != 0) ? 1.f : 0.f;

    // ---- deferred softmax: p = exp(s)*vis, accumulate l, pack to Ps ----
    #pragma unroll
    for (int mb=0;mb<2;++mb){
      #pragma unroll
      for (int n=0;n<4;++n){
        int coln = ((n ^ quad)<<4) + l15;      // XOR swizzle -> conflict-free
        #pragma unroll
        for (int rr=0;rr<4;++rr){
          float p = __expf(s4[mb][n][rr]) * vf[n];
          l_r[mb][rr] += p;
          Ps[wave][(mb<<4)+(quad<<2)+rr][coln] = (u16)f2bf(p);
        }
      }
    }
    asm volatile("s_waitcnt lgkmcnt(0)" ::: "memory");

    // ---- P A-frags (swizzle-aware reads) ----
    short8 pa[2][2];
    #pragma unroll
    for (int mb=0;mb<2;++mb){
      pa[mb][0] = *(const short8*)&Ps[wave][(mb<<4)+l15]
                    [ ((((quad>>1)  ) ^ sw)<<4) + ((quad&1)<<3) ];
      pa[mb][1] = *(const short8*)&Ps[wave][(mb<<4)+l15]
                    [ ((((quad>>1)+2) ^ sw)<<4) + ((quad&1)<<3) ];
    }

    // ---- O += P V ----
    #pragma unroll
    for (int s=0;s<4;++s){
      short8 vb0 = *(const short8*)&Vs[(s<<4)+l15][quad<<3];
      short8 vb1 = *(const short8*)&Vs[(s<<4)+l15][(quad<<3)+32];
      #pragma unroll
      for (int mb=0;mb<2;++mb){
        acc[mb][s] = mfma16(pa[mb][0], vb0, acc[mb][s]);
        acc[mb][s] = mfma16(pa[mb][1], vb1, acc[mb][s]);
      }
    }
  }

  // ---- epilogue ----
  #pragma unroll
  for (int mb=0;mb<2;++mb){
    #pragma unroll
    for (int rr=0;rr<4;++rr){
      float t = l_r[mb][rr];
      t += __shfl_xor(t,1); t += __shfl_xor(t,2);
      t += __shfl_xor(t,4); t += __shfl_xor(t,8);
      int qrow = (qt<<7) + (wave<<5) + (mb<<4) + (quad<<2) + rr;
      int qv = visb[qrow];
      float invl = (qv != 0 && t > 0.f) ? 1.f/t : 0.f;
      float* obase = out + ((((size_t)b*Nn + qrow)*Hh + h)<<6);
      #pragma unroll
      for (int s=0;s<4;++s)
        obase[(s<<4)+l15] = acc[mb][s][rr]*invl;
    }
  }
}

// ============================================================
// Fallback (R2 kernel, inline sincos) — used if ws too small
// ============================================================
__device__ __forceinline__ void stage_rope_row_fb(const float* __restrict__ src,
                                                  u16 (*dst)[72],
                                                  int n_global, int sr, int d0)
{
  const float4* g = (const float4*)src;
  float4 a0 = g[0], a1 = g[1], a2 = g[2], a3 = g[3];
  float xx[16] = {a0.x,a0.y,a0.z,a0.w, a1.x,a1.y,a1.z,a1.w,
                  a2.x,a2.y,a2.z,a2.w, a3.x,a3.y,a3.z,a3.w};
  uint32_t w[8];
  #pragma unroll
  for (int j=0;j<8;++j){
    int i = (d0>>1)+j;
    float inv = exp2f(-(float)i * ROPE_K);
    float ang = (float)n_global * inv;
    float sn, cs; sincosf(ang, &sn, &cs);
    float x0 = xx[2*j], x1 = xx[2*j+1];
    float q0 = x0*cs - x1*sn;
    float q1 = x1*cs + x0*sn;
    w[j] = f2bf(q0) | (f2bf(q1)<<16);
  }
  *(uint4*)&dst[sr][d0]   = make_uint4(w[0],w[1],w[2],w[3]);
  *(uint4*)&dst[sr][d0+8] = make_uint4(w[4],w[5],w[6],w[7]);
}

__global__ __launch_bounds__(256,2) void attn_fallback(
    const float* __restrict__ xq, const float* __restrict__ xk,
    const float* __restrict__ xv, const int* __restrict__ vis,
    float* __restrict__ out)
{
  __shared__ u16 Qs[64][72];
  __shared__ u16 Ks[64][72];
  __shared__ u16 Vt[64][72];
  __shared__ u16 Ps[4][16][72];
  __shared__ float viss[64];

  const int tid  = threadIdx.x;
  const int wave = tid >> 6;
  const int lane = tid & 63;
  const int l15  = lane & 15;
  const int quad = lane >> 4;

  const int bid = blockIdx.x;
  const int qt = bid & 15;
  const int h  = (bid >> 4) & 7;
  const int b  = bid >> 7;

  const int sr = tid >> 2;
  const int d0 = (tid & 3) << 4;

  {
    int ng = (qt<<6) + sr;
    const float* src = xq + ((((size_t)b*Nn + ng)*Hh + h)<<6) + d0;
    stage_rope_row_fb(src, Qs, ng, sr, d0);
  }
  __syncthreads();

  short8 qa0 = *(const short8*)&Qs[(wave<<4)+l15][quad<<3];
  short8 qa1 = *(const short8*)&Qs[(wave<<4)+l15][(quad<<3)+32];

  f32x4 acc[4];
  #pragma unroll
  for (int s=0;s<4;++s) acc[s] = (f32x4){0.f,0.f,0.f,0.f};
  float m_r[4], l_r[4];
  #pragma unroll
  for (int rr=0;rr<4;++rr){ m_r[rr] = -1e30f; l_r[rr] = 0.f; }

  for (int kt=0; kt<16; ++kt){
    __syncthreads();
    {
      int ng = (kt<<6) + sr;
      const float* src = xk + ((((size_t)b*Nn + ng)*Hh + h)<<6) + d0;
      stage_rope_row_fb(src, Ks, ng, sr, d0);
    }
    {
      int ng = (kt<<6) + sr;
      const float4* g = (const float4*)(xv + ((((size_t)b*Nn + ng)*Hh + h)<<6) + d0);
      float4 a0 = g[0], a1 = g[1], a2 = g[2], a3 = g[3];
      float vv16[16] = {a0.x,a0.y,a0.z,a0.w, a1.x,a1.y,a1.z,a1.w,
                        a2.x,a2.y,a2.z,a2.w, a3.x,a3.y,a3.z,a3.w};
      #pragma unroll
      for (int j=0;j<16;++j) Vt[d0+j][sr] = (u16)f2bf(vv16[j]);
    }
    if (tid < 64) viss[tid] = (vis[b*Nn + (kt<<6) + tid] != 0) ? 1.f : 0.f;
    __syncthreads();

    f32x4 s4[4];
    #pragma unroll
    for (int n=0;n<4;++n){
      short8 kb0 = *(const short8*)&Ks[(n<<4)+l15][quad<<3];
      short8 kb1 = *(const short8*)&Ks[(n<<4)+l15][(quad<<3)+32];
      f32x4 t = (f32x4){0.f,0.f,0.f,0.f};
      t = mfma16(qa0, kb0, t);
      t = mfma16(qa1, kb1, t);
      s4[n] = t;
    }
    float vv[4];
    #pragma unroll
    for (int n=0;n<4;++n) vv[n] = viss[(n<<4)+l15];

    float p[4][4];
    #pragma unroll
    for (int rr=0; rr<4; ++rr){
      float sc[4];
      #pragma unroll
      for (int n=0;n<4;++n) sc[n] = (vv[n] > 0.f) ? s4[n][rr]*0.125f : -1e30f;
      float tm = fmaxf(fmaxf(sc[0],sc[1]), fmaxf(sc[2],sc[3]));
      tm = fmaxf(tm, __shfl_xor(tm,1));
      tm = fmaxf(tm, __shfl_xor(tm,2));
      tm = fmaxf(tm, __shfl_xor(tm,4));
      tm = fmaxf(tm, __shfl_xor(tm,8));
      float mnew  = fmaxf(m_r[rr], tm);
      float alpha = __expf(m_r[rr] - mnew);
      m_r[rr] = mnew;
      float psum = 0.f;
      #pragma unroll
      for (int n=0;n<4;++n){
        float pv = (vv[n] > 0.f) ? __expf(sc[n] - mnew) : 0.f;
        p[n][rr] = pv; psum += pv;
      }
      l_r[rr] = l_r[rr]*alpha + psum;
      #pragma unroll
      for (int s=0;s<4;++s) acc[s][rr] *= alpha;
    }

    #pragma unroll
    for (int n=0;n<4;++n)
      #pragma unroll
      for (int rr=0;rr<4;++rr)
        Ps[wave][(quad<<2)+rr][(n<<4)+l15] = (u16)f2bf(p[n][rr]);
    asm volatile("s_waitcnt lgkmcnt(0)" ::: "memory");
    short8 pa0 = *(const short8*)&Ps[wave][l15][quad<<3];
    short8 pa1 = *(const short8*)&Ps[wave][l15][(quad<<3)+32];

    #pragma unroll
    for (int s=0;s<4;++s){
      short8 vb0 = *(const short8*)&Vt[(s<<4)+l15][quad<<3];
      short8 vb1 = *(const short8*)&Vt[(s<<4)+l15][(quad<<3)+32];
      acc[s] = mfma16(pa0, vb0, acc[s]);
      acc[s] = mfma16(pa1, vb1, acc[s]);
    }
  }

  #pragma unroll
  for (int rr=0;rr<4;++rr){
    float t = l_r[rr];
    t += __shfl_xor(t,1); t += __shfl_xor(t,2);
    t += __shfl_xor(t,4); t += __shfl_xor(t,8);
    int row = (qt<<6) + (wave<<4) + (quad<<2) + rr;
    int qv  = vis[b*Nn + row];
    float invl = (qv != 0 && t > 0.f) ? 1.f/t : 0.f;
    size_t obase = (((size_t)b*Nn + row)*Hh + h) << 6;
    #pragma unroll
    for (int s=0;s<4;++s)
      out[obase + (s<<4) + l15] = acc[s][rr]*invl;
  }
}

extern "C" void kernel_launch(void* const* d_in, const int* in_sizes, int n_in,
                              void* d_out, int out_size, void* d_ws, size_t ws_size,
                              hipStream_t stream)
{
  const float* xq = (const float*)d_in[0];
  const float* xk = (const float*)d_in[1];
  const float* xv = (const float*)d_in[2];
  const int* vis  = (const int*)d_in[3];
  float* out = (float*)d_out;

  const size_t kv_elems = (size_t)Bb*Hh*Nn*Dd;           // 8.39M
  const size_t need = 2*kv_elems*sizeof(u16);            // 33.6 MB

  if (d_ws != nullptr && ws_size >= need){
    u16* Kr = (u16*)d_ws;
    u16* Vt = Kr + kv_elems;
    prepass_kernel<<<dim3(Bb*Hh*(Nn/64)), dim3(256), 0, stream>>>(xk, xv, Kr, Vt);
    attn2_kernel<<<dim3(Bb*Hh*(Nn/128)), dim3(256), 0, stream>>>(xq, Kr, Vt, vis, out);
  } else {
    attn_fallback<<<dim3(Bb*Hh*(Nn/64)), dim3(256), 0, stream>>>(xq, xk, xv, vis, out);
  }
}